// Round 9
// baseline (198.171 us; speedup 1.0000x reference)
//
#include <hip/hip_runtime.h>
#include <hip/hip_bf16.h>
#include <hip/hip_cooperative_groups.h>

namespace cg = cooperative_groups;

// Sizes
#define NB 8
#define NC 4
#define NN 1024
#define ND 96
#define NHH 3
#define DKV 32
#define NBC (NB*NC)        // 32
#define NHEAD (NBC*NHH)    // 96
#define NROWS (NBC*NN)     // 32768
// log2(e) / sqrt(32)  (folded into K at projection time)
#define C1 0.25503486910638953f
#define EPSV 1e-5f

using short8 = __attribute__((ext_vector_type(8))) short;
using f32x4  = __attribute__((ext_vector_type(4))) float;
using f32x16 = __attribute__((ext_vector_type(16))) float;

__device__ __forceinline__ short bf16_of(float f) {
  __hip_bfloat16 h = __float2bfloat16(f);
  return __builtin_bit_cast(short, h);
}
__device__ __forceinline__ float f_of_bf16(short s) {
  return __bfloat162float(__builtin_bit_cast(__hip_bfloat16, s));
}

__device__ __forceinline__ short8 load_cvt8(const float* p) {
  float4 f0 = *(const float4*)p;
  float4 f1 = *(const float4*)(p + 4);
  short8 v;
  v[0] = bf16_of(f0.x); v[1] = bf16_of(f0.y); v[2] = bf16_of(f0.z); v[3] = bf16_of(f0.w);
  v[4] = bf16_of(f1.x); v[5] = bf16_of(f1.y); v[6] = bf16_of(f1.z); v[7] = bf16_of(f1.w);
  return v;
}

// ---------------------------------------------------------------------------
// Fused cooperative kernel: P(proj) -> S(stats+V') -> C(ctx) -> O(fc+LN).
// grid <= 768 blocks x 256 thr (3 blocks/CU); 20KB smem union per phase.
// All phase bodies are the round-7 kernels as grid-stride loops (stride
// multiple of 96 preserves same-head/same-XCD affinity).
// ---------------------------------------------------------------------------
__global__ __launch_bounds__(256, 3) void fused_kernel(
    const float* xq, const float* xk, const float* xv,
    const float* Wq, const float* Wk, const float* Wv,
    const float* Wfc, const float* gamma, const float* beta,
    short* qb, short* kbuf, short* vtb, short* vb, short* ctx,
    float* out)
{
  __shared__ __align__(16) char smem[20480];
  cg::grid_group grid = cg::this_grid();
  const int t = threadIdx.x;
  const int wave = t >> 6, lane = t & 63;
  const int g16 = lane >> 4, li16 = lane & 15;

  // ================= Phase P: projections =================
  {
    short* wlds = (short*)smem;                       // [96][104]
    for (int u = (int)blockIdx.x; u < 1536; u += (int)gridDim.x) {
      const int p = u >> 9;                           // 0..2
      const int blkrow0 = (u & 511) * 64;
      const float* x = (p == 0) ? xq : (p == 1) ? xk : xv;
      const float* W = (p == 0) ? Wq : (p == 1) ? Wk : Wv;
      short* dst = (p == 0) ? qb : (p == 1) ? kbuf : vb;
      const float sc = (p == 1) ? C1 : 1.0f;

      __syncthreads();                                // prior unit done with wlds
      for (int idx = t; idx < 96*96; idx += 256)
        wlds[(idx/96)*104 + (idx%96)] = bf16_of(W[idx]);
      __syncthreads();

      const int row0 = blkrow0 + wave * 16;
      const int acol = g16 * 8;
      const float* xr = x + (size_t)(row0 + li16)*ND + acol;
      const short8 a0 = load_cvt8(xr);
      const short8 a1 = load_cvt8(xr + 32);
      const short8 a2 = load_cvt8(xr + 64);
#pragma unroll
      for (int tt = 0; tt < 6; ++tt) {
        f32x4 acc = {0.f, 0.f, 0.f, 0.f};
        const short* wr = wlds + (tt*16 + li16)*104 + acol;
        acc = __builtin_amdgcn_mfma_f32_16x16x32_bf16(a0, *(const short8*)(wr),      acc, 0, 0, 0);
        acc = __builtin_amdgcn_mfma_f32_16x16x32_bf16(a1, *(const short8*)(wr + 32), acc, 0, 0, 0);
        acc = __builtin_amdgcn_mfma_f32_16x16x32_bf16(a2, *(const short8*)(wr + 64), acc, 0, 0, 0);
        const int e = tt*16 + li16;
        const int h = e >> 5, dd = e & 31;
#pragma unroll
        for (int r = 0; r < 4; ++r) {
          const int n = row0 + g16*4 + r;
          const int bc = n >> 10, nn = n & 1023;
          const int head = bc*NHH + h;
          dst[((size_t)head*NN + nn)*DKV + dd] = bf16_of(acc[r] * sc);
        }
      }
    }
  }
  grid.sync();

  // ================= Phase S: column sums + V' transpose =================
  {
    short* s_q  = (short*)smem;                       // [2][64][40] = 10240B
    float* s_is = (float*)(smem + 10240);             // [64]        = 256B
    short* s_t  = (short*)(smem + 10496);             // [32][64]    = 4096B
    for (int u = (int)blockIdx.x; u < 1536; u += (int)gridDim.x) {
      const int head = u % NHEAD;                     // XCD-aware
      const int kblk = u / NHEAD;                     // 0..15
      const int kb0 = kblk*64;
      const int k0 = kb0 + wave*16;

      const short8 af = *(const short8*)(kbuf + ((size_t)head*NN + k0 + li16)*DKV + g16*8);
      const short* qhead = qb + (size_t)head*NN*DKV;
      const int srow = t >> 2;                        // 0..63
      const int sseg = (t & 3) * 8;

      f32x4 s0 = {0.f,0.f,0.f,0.f};

      __syncthreads();                                // prior unit done with s_q/s_t
      *(short8*)(s_q + srow*40 + sseg) = *(const short8*)(qhead + (size_t)srow*DKV + sseg);
      __syncthreads();

      for (int qc = 0; qc < 16; ++qc) {
        const int cur = qc & 1;
        short8 nxt;
        if (qc < 15)
          nxt = *(const short8*)(qhead + (size_t)((qc+1)*64 + srow)*DKV + sseg);
#pragma unroll
        for (int qt = 0; qt < 4; ++qt) {
          const short8 bf = *(const short8*)(s_q + cur*2560 + (qt*16 + li16)*40 + g16*8);
          f32x4 z = {0.f,0.f,0.f,0.f};
          f32x4 d = __builtin_amdgcn_mfma_f32_16x16x32_bf16(af, bf, z, 0, 0, 0);
#pragma unroll
          for (int r = 0; r < 4; ++r)
            s0[r] += __builtin_amdgcn_exp2f(d[r]);
        }
        if (qc < 15)
          *(short8*)(s_q + (cur^1)*2560 + srow*40 + sseg) = nxt;
        __syncthreads();
      }

#pragma unroll
      for (int ms = 1; ms <= 8; ms <<= 1) {
#pragma unroll
        for (int r = 0; r < 4; ++r)
          s0[r] += __shfl_xor(s0[r], ms);
      }
      if (li16 == 0) {
#pragma unroll
        for (int r = 0; r < 4; ++r)
          s_is[wave*16 + g16*4 + r] = 1.0f / s0[r];
      }
      __syncthreads();

      // V' phase A: scale + scatter into LDS transpose
      {
        const int nl = t >> 2;                        // 0..63 local k
        const int dvs = (t & 3) * 8;
        const float isv = s_is[nl];
        const short* vrow = vb + ((size_t)head*NN + kb0 + nl)*DKV + dvs;
        short8 v0 = *(const short8*)(vrow);
#pragma unroll
        for (int j = 0; j < 8; ++j) {
          const int dv = dvs + j;
          s_t[dv*64 + (((nl*2) ^ ((dv & 7) << 4)) >> 1)] = bf16_of(isv * f_of_bf16(v0[j]));
        }
      }
      __syncthreads();

      // V' phase B: coalesced write to vtb [head][dv][n]
      {
        const int dv = t >> 3, ns = t & 7;
        short8 v = *(const short8*)(s_t + dv*64 + (((ns*16) ^ ((dv & 7) << 4)) >> 1));
        *(short8*)(vtb + ((size_t)head*DKV + dv)*NN + kb0 + ns*8) = v;
      }
    }
  }
  grid.sync();

  // ================= Phase C: context (tau-permuted K, P-in-register) =====
  {
    short* s_k  = (short*)smem;                       // [2][64][40] = 10240B
    short* s_vt = (short*)(smem + 10240);             // [2][32][72] = 9216B
    for (int u = (int)blockIdx.x; u < 768; u += (int)gridDim.x) {
      const int head = u % NHEAD;                     // XCD-aware
      const int qtile = u / NHEAD;                    // 0..7
      const int li = lane & 31, hi = lane >> 5;
      const int q0 = qtile*128 + wave*32;

      const short* qrow = qb + ((size_t)head*NN + q0 + li)*DKV;
      const short8 qf0 = *(const short8*)(qrow + hi*8);
      const short8 qf1 = *(const short8*)(qrow + 16 + hi*8);

      f32x16 acc = {0.f,0.f,0.f,0.f,0.f,0.f,0.f,0.f,0.f,0.f,0.f,0.f,0.f,0.f,0.f,0.f};

      const int krow = t >> 2, kseg = (t & 3) * 8;    // stage K: 64 x 32
      const int krowp = (krow & 51) | ((krow & 4) << 1) | ((krow & 8) >> 1);  // tau
      const int vrow = t >> 3, vseg = (t & 7) * 8;    // stage V': 32 x 64
      const short* kgp = kbuf + (size_t)head*NN*DKV;
      const short* vgp = vtb  + (size_t)head*DKV*NN;

      __syncthreads();                                // prior unit done with s_k/s_vt
      *(short8*)(s_k + krowp*40 + kseg)  = *(const short8*)(kgp + (size_t)krow*DKV + kseg);
      *(short8*)(s_vt + vrow*72 + vseg)  = *(const short8*)(vgp + (size_t)vrow*NN + vseg);
      __syncthreads();

      for (int kc = 0; kc < 16; ++kc) {
        const int cur = kc & 1;
        short8 nk, nv;
        if (kc < 15) {
          nk = *(const short8*)(kgp + (size_t)((kc+1)*64 + krow)*DKV + kseg);
          nv = *(const short8*)(vgp + (size_t)vrow*NN + (kc+1)*64 + vseg);
        }

#pragma unroll
        for (int kt = 0; kt < 2; ++kt) {
          const short8 a0 = *(const short8*)(s_k + cur*2560 + (kt*32 + li)*40 + hi*8);
          const short8 a1 = *(const short8*)(s_k + cur*2560 + (kt*32 + li)*40 + 16 + hi*8);
          f32x16 sT = {0.f,0.f,0.f,0.f,0.f,0.f,0.f,0.f,0.f,0.f,0.f,0.f,0.f,0.f,0.f,0.f};
          sT = __builtin_amdgcn_mfma_f32_32x32x16_bf16(a0, qf0, sT, 0, 0, 0);
          sT = __builtin_amdgcn_mfma_f32_32x32x16_bf16(a1, qf1, sT, 0, 0, 0);
          // exp'd regs 0-7 / 8-15 ARE the PV A-frags (tau row permutation)
          short8 pa0, pa1;
#pragma unroll
          for (int j = 0; j < 8; ++j) {
            pa0[j] = bf16_of(__builtin_amdgcn_exp2f(sT[j]));
            pa1[j] = bf16_of(__builtin_amdgcn_exp2f(sT[8 + j]));
          }
          const short8 vfa = *(const short8*)(s_vt + cur*2304 + li*72 + kt*32 + hi*8);
          const short8 vfb = *(const short8*)(s_vt + cur*2304 + li*72 + kt*32 + 16 + hi*8);
          acc = __builtin_amdgcn_mfma_f32_32x32x16_bf16(pa0, vfa, acc, 0, 0, 0);
          acc = __builtin_amdgcn_mfma_f32_32x32x16_bf16(pa1, vfb, acc, 0, 0, 0);
        }

        if (kc < 15) {
          *(short8*)(s_k + (cur^1)*2560 + krowp*40 + kseg) = nk;
          *(short8*)(s_vt + (cur^1)*2304 + vrow*72 + vseg) = nv;
        }
        __syncthreads();
      }

      const int bc = head / NHH, h = head % NHH;
#pragma unroll
      for (int reg = 0; reg < 16; ++reg) {
        const int q = q0 + (reg & 3) + 8*(reg >> 2) + 4*hi;
        ctx[((size_t)(bc*NN + q))*ND + h*DKV + li] = bf16_of(acc[reg]);
      }
    }
  }
  grid.sync();

  // ================= Phase O: out = LN(ctx @ Wfc^T + resid) =================
  {
    short* wlds = (short*)smem;                       // [96][104]
    for (int idx = t; idx < 96*96; idx += 256)
      wlds[(idx/96)*104 + (idx%96)] = bf16_of(Wfc[idx]);
    __syncthreads();

    for (int u = (int)blockIdx.x; u < 512; u += (int)gridDim.x) {
      const int row0 = u*64 + wave*16;

      const short* ar = ctx + (size_t)(row0 + li16)*ND + g16*8;
      const short8 a0 = *(const short8*)(ar);
      const short8 a1 = *(const short8*)(ar + 32);
      const short8 a2 = *(const short8*)(ar + 64);

      float o[6][4];
#pragma unroll
      for (int tt = 0; tt < 6; ++tt) {
        f32x4 acc = {0.f, 0.f, 0.f, 0.f};
        const short* wr = wlds + (tt*16 + li16)*104 + g16*8;
        acc = __builtin_amdgcn_mfma_f32_16x16x32_bf16(a0, *(const short8*)(wr),      acc, 0, 0, 0);
        acc = __builtin_amdgcn_mfma_f32_16x16x32_bf16(a1, *(const short8*)(wr + 32), acc, 0, 0, 0);
        acc = __builtin_amdgcn_mfma_f32_16x16x32_bf16(a2, *(const short8*)(wr + 64), acc, 0, 0, 0);
#pragma unroll
        for (int r = 0; r < 4; ++r)
          o[tt][r] = acc[r] + xq[(size_t)(row0 + g16*4 + r)*ND + tt*16 + li16];
      }

      float s1v[4], s2v[4];
#pragma unroll
      for (int r = 0; r < 4; ++r) {
        float a = 0.f, b = 0.f;
#pragma unroll
        for (int tt = 0; tt < 6; ++tt) { a += o[tt][r]; b += o[tt][r]*o[tt][r]; }
        s1v[r] = a; s2v[r] = b;
      }
#pragma unroll
      for (int ms = 1; ms <= 8; ms <<= 1) {
#pragma unroll
        for (int r = 0; r < 4; ++r) {
          s1v[r] += __shfl_xor(s1v[r], ms);
          s2v[r] += __shfl_xor(s2v[r], ms);
        }
      }
      float mean[4], rs[4];
#pragma unroll
      for (int r = 0; r < 4; ++r) {
        mean[r] = s1v[r] * (1.0f/96.0f);
        float var = s2v[r]*(1.0f/96.0f) - mean[r]*mean[r];
        rs[r] = rsqrtf(var + EPSV);
      }
#pragma unroll
      for (int tt = 0; tt < 6; ++tt) {
        const int e = tt*16 + li16;
        const float gg = gamma[e], bb = beta[e];
#pragma unroll
        for (int r = 0; r < 4; ++r)
          out[(size_t)(row0 + g16*4 + r)*ND + e] = (o[tt][r] - mean[r])*rs[r]*gg + bb;
      }
    }
  }
}

// ---------------------------------------------------------------------------
extern "C" void kernel_launch(void* const* d_in, const int* in_sizes, int n_in,
                              void* d_out, int out_size, void* d_ws, size_t ws_size,
                              hipStream_t stream) {
  (void)in_sizes; (void)n_in; (void)out_size; (void)ws_size;
  const float* xq    = (const float*)d_in[0];
  const float* xk    = (const float*)d_in[1];
  const float* xv    = (const float*)d_in[2];
  const float* Wq    = (const float*)d_in[3];
  const float* Wk    = (const float*)d_in[4];
  const float* Wv    = (const float*)d_in[5];
  const float* Wfc   = (const float*)d_in[6];
  const float* gamma = (const float*)d_in[7];
  const float* beta  = (const float*)d_in[8];
  float* out = (float*)d_out;

  // Workspace layout (25.17 MB — ctx aliases vb, dead after phase S; proven
  // safe since round 4).
  short* qb   = (short*)d_ws;                        // [head][n][32]
  short* kbuf = qb   + (size_t)NHEAD*NN*DKV;         // [head][n][32] (x C1)
  short* vtb  = kbuf + (size_t)NHEAD*NN*DKV;         // [head][32][n] = is[k]*V
  short* vb   = vtb  + (size_t)NHEAD*NN*DKV;         // [head][n][32] (dead after S)
  short* ctx  = vb;                                  // [bc*n][96] (aliases vb)

  // Cooperative grid: want 768 (3 blocks/CU); clamp to queried occupancy so
  // the co-residency requirement can never fail. Host-side query only —
  // deterministic and graph-capture-safe.
  int blocksPerCU = 0;
  hipOccupancyMaxActiveBlocksPerMultiprocessor(&blocksPerCU, fused_kernel, 256, 0);
  if (blocksPerCU < 1) blocksPerCU = 1;
  int nblk = blocksPerCU * 256;
  if (nblk > 768) nblk = 768;

  void* args[] = { &xq, &xk, &xv, &Wq, &Wk, &Wv, &Wfc, &gamma, &beta,
                   &qb, &kbuf, &vtb, &vb, &ctx, &out };
  hipLaunchCooperativeKernel((void*)fused_kernel, dim3(nblk), dim3(256),
                             args, 0, stream);
}

// Round 10
// 192.784 us; speedup vs baseline: 1.0279x; 1.0279x over previous
//
#include <hip/hip_runtime.h>
#include <hip/hip_bf16.h>

// Sizes
#define NB 8
#define NC 4
#define NN 1024
#define ND 96
#define NHH 3
#define DKV 32
#define NBC (NB*NC)        // 32
#define NHEAD (NBC*NHH)    // 96
#define NROWS (NBC*NN)     // 32768
// log2(e) / sqrt(32)  (folded into K at projection time)
#define C1 0.25503486910638953f
#define EPSV 1e-5f

using short8 = __attribute__((ext_vector_type(8))) short;
using f32x4  = __attribute__((ext_vector_type(4))) float;
using f32x16 = __attribute__((ext_vector_type(16))) float;

__device__ __forceinline__ short bf16_of(float f) {
  __hip_bfloat16 h = __float2bfloat16(f);
  return __builtin_bit_cast(short, h);
}
__device__ __forceinline__ float f_of_bf16(short s) {
  return __bfloat162float(__builtin_bit_cast(__hip_bfloat16, s));
}

__device__ __forceinline__ short8 load_cvt8(const float* p) {
  float4 f0 = *(const float4*)p;
  float4 f1 = *(const float4*)(p + 4);
  short8 v;
  v[0] = bf16_of(f0.x); v[1] = bf16_of(f0.y); v[2] = bf16_of(f0.z); v[3] = bf16_of(f0.w);
  v[4] = bf16_of(f1.x); v[5] = bf16_of(f1.y); v[6] = bf16_of(f1.z); v[7] = bf16_of(f1.w);
  return v;
}

// ---------------------------------------------------------------------------
// Kernel 1: projections, p split across blocks; x staged via LDS (coalesced).
// Block 0 also zeroes the ticket counters for the ctx/out merge.
// grid 1536 = 3 x 512, block 256.
// ---------------------------------------------------------------------------
__global__ __launch_bounds__(256) void proj_kernel(
    const float* __restrict__ xq, const float* __restrict__ xk, const float* __restrict__ xv,
    const float* __restrict__ Wq, const float* __restrict__ Wk, const float* __restrict__ Wv,
    short* __restrict__ qb, short* __restrict__ kb, short* __restrict__ vb,
    int* __restrict__ cnt)
{
  __shared__ __align__(16) short wlds[96][104];
  __shared__ __align__(16) short xlds[64][104];
  const int t = threadIdx.x;
  const int p = blockIdx.x >> 9;               // 0..2
  const int blkrow0 = (blockIdx.x & 511) * 64;

  if (blockIdx.x == 0) cnt[t] = 0;             // 256 tickets (32 bc x 8 qtiles)

  const float* x = (p == 0) ? xq : (p == 1) ? xk : xv;
  const float* W = (p == 0) ? Wq : (p == 1) ? Wk : Wv;
  short* dst = (p == 0) ? qb : (p == 1) ? kb : vb;
  const float sc = (p == 1) ? C1 : 1.0f;

  for (int idx = t; idx < 96*96; idx += 256)
    wlds[idx/96][idx%96] = bf16_of(W[idx]);
#pragma unroll
  for (int it = 0; it < 3; ++it) {
    const int f = it*2048 + t*8;               // 96%8==0: no row straddle
    const int row = f / 96, col = f % 96;
    *(short8*)&xlds[row][col] = load_cvt8(x + (size_t)(blkrow0 + row)*ND + col);
  }
  __syncthreads();

  const int wave = t >> 6, lane = t & 63;
  const int g = lane >> 4, li = lane & 15;
  const int row0 = blkrow0 + wave * 16;
  const int acol = g * 8;

  const short8 a0 = *(const short8*)&xlds[wave*16 + li][acol];
  const short8 a1 = *(const short8*)&xlds[wave*16 + li][32 + acol];
  const short8 a2 = *(const short8*)&xlds[wave*16 + li][64 + acol];
#pragma unroll
  for (int tt = 0; tt < 6; ++tt) {
    f32x4 acc = {0.f, 0.f, 0.f, 0.f};
    const short* wr = &wlds[tt*16 + li][acol];
    acc = __builtin_amdgcn_mfma_f32_16x16x32_bf16(a0, *(const short8*)(wr),      acc, 0, 0, 0);
    acc = __builtin_amdgcn_mfma_f32_16x16x32_bf16(a1, *(const short8*)(wr + 32), acc, 0, 0, 0);
    acc = __builtin_amdgcn_mfma_f32_16x16x32_bf16(a2, *(const short8*)(wr + 64), acc, 0, 0, 0);
    const int e = tt*16 + li;
    const int h = e >> 5, dd = e & 31;
#pragma unroll
    for (int r = 0; r < 4; ++r) {
      const int n = row0 + g*4 + r;
      const int bc = n >> 10, nn = n & 1023;
      const int head = bc*NHH + h;
      dst[((size_t)head*NN + nn)*DKV + dd] = bf16_of(acc[r] * sc);
    }
  }
}

// ---------------------------------------------------------------------------
// Kernel 2: column softmax sums + V' = diag(1/sum)*V transposed.
// 64 k per block (wave owns 16 k-rows), Q chunks double-buffered in LDS.
// XCD-aware: head = blockIdx%96. grid 96*16, block 256.
// ---------------------------------------------------------------------------
__global__ __launch_bounds__(256) void stats_kernel(
    const short* __restrict__ qb, const short* __restrict__ kb,
    const short* __restrict__ vb, short* __restrict__ vtb)
{
  __shared__ __align__(16) short s_q[2][64][40];
  __shared__ float s_is[64];
  __shared__ __align__(16) short s_t[32][64];    // V' transpose buf (swizzled)

  const int t = threadIdx.x, wave = t >> 6, lane = t & 63;
  const int g = lane >> 4, li = lane & 15;
  const int head = blockIdx.x % NHEAD;           // XCD-aware
  const int kblk = blockIdx.x / NHEAD;           // 0..15
  const int kb0 = kblk*64;
  const int k0 = kb0 + wave*16;

  const short8 af = *(const short8*)(kb + ((size_t)head*NN + k0 + li)*DKV + g*8);

  const short* qhead = qb + (size_t)head*NN*DKV;
  const int srow = t >> 2;          // 0..63
  const int sseg = (t & 3) * 8;

  f32x4 s0 = {0.f,0.f,0.f,0.f};

  *(short8*)&s_q[0][srow][sseg] = *(const short8*)(qhead + (size_t)srow*DKV + sseg);
  __syncthreads();

  for (int qc = 0; qc < 16; ++qc) {
    const int cur = qc & 1;
    short8 nxt;
    if (qc < 15)
      nxt = *(const short8*)(qhead + (size_t)((qc+1)*64 + srow)*DKV + sseg);
#pragma unroll
    for (int qt = 0; qt < 4; ++qt) {
      const short8 bf = *(const short8*)&s_q[cur][qt*16 + li][g*8];
      f32x4 z = {0.f,0.f,0.f,0.f};
      f32x4 d = __builtin_amdgcn_mfma_f32_16x16x32_bf16(af, bf, z, 0, 0, 0);
#pragma unroll
      for (int r = 0; r < 4; ++r)
        s0[r] += __builtin_amdgcn_exp2f(d[r]);
    }
    if (qc < 15)
      *(short8*)&s_q[cur^1][srow][sseg] = nxt;
    __syncthreads();
  }

#pragma unroll
  for (int ms = 1; ms <= 8; ms <<= 1) {
#pragma unroll
    for (int r = 0; r < 4; ++r)
      s0[r] += __shfl_xor(s0[r], ms);
  }
  if (li == 0) {
#pragma unroll
    for (int r = 0; r < 4; ++r)
      s_is[wave*16 + g*4 + r] = 1.0f / s0[r];
  }
  __syncthreads();

  // ---- V' phase A: read vb rows, scale by is[n], scatter into LDS transpose
  {
    const int nl = t >> 2;              // 0..63 (local k)
    const int dvs = (t & 3) * 8;        // dv segment base
    const float isv = s_is[nl];
    const short* vrow = vb + ((size_t)head*NN + kb0 + nl)*DKV + dvs;
    short8 v0 = *(const short8*)(vrow);
    short* st = &s_t[0][0];
#pragma unroll
    for (int j = 0; j < 8; ++j) {
      const int dv = dvs + j;
      st[dv*64 + (((nl*2) ^ ((dv & 7) << 4)) >> 1)] = bf16_of(isv * f_of_bf16(v0[j]));
    }
  }
  __syncthreads();

  // ---- V' phase B: coalesced write to vtb [head][dv][n]
  {
    const short* st = &s_t[0][0];
    const int dv = t >> 3, ns = t & 7;
    short8 v = *(const short8*)(st + dv*64 + (((ns*16) ^ ((dv & 7) << 4)) >> 1));
    *(short8*)(vtb + ((size_t)head*DKV + dv)*NN + kb0 + ns*8) = v;
  }
}

// ---------------------------------------------------------------------------
// Kernel 3: context + fused epilogue. 32x32x16 MFMAs; tau-permuted K staging
// so exp'd S^T regs ARE the PV A-fragments. After writing its ctx slice, each
// block takes a ticket on (bc,qtile); the THIRD finisher (all 3 heads done)
// computes out = LN(ctx @ Wfc^T + resid) for those 128 rows, reusing LDS.
// Fence-release / count / fence-acquire: deterministic, no waiting.
// XCD-aware: head = blockIdx%96. grid 96*8, block 256 (4 waves x 32 q).
// ---------------------------------------------------------------------------
__global__ __launch_bounds__(256) void ctx_kernel(
    const short* __restrict__ qb, const short* __restrict__ kb,
    const short* __restrict__ vtb, const float* __restrict__ resid,
    const float* __restrict__ Wfc, const float* __restrict__ gamma,
    const float* __restrict__ beta, short* __restrict__ ctx,
    int* __restrict__ cnt, float* __restrict__ out)
{
  __shared__ __align__(16) char smem[20480];     // union: {s_k,s_vt} | wlds
  __shared__ int s_flag;
  short* s_k  = (short*)smem;                    // [2][64][40] = 10240B
  short* s_vt = (short*)(smem + 10240);          // [2][32][72] = 9216B

  const int t = threadIdx.x, wave = t >> 6, lane = t & 63;
  const int li = lane & 31, hi = lane >> 5;
  const int head = blockIdx.x % NHEAD;           // XCD-aware
  const int qtile = blockIdx.x / NHEAD;          // 0..7
  const int q0 = qtile*128 + wave*32;

  const short* qrow = qb + ((size_t)head*NN + q0 + li)*DKV;
  const short8 qf0 = *(const short8*)(qrow + hi*8);
  const short8 qf1 = *(const short8*)(qrow + 16 + hi*8);

  f32x16 acc = {0.f,0.f,0.f,0.f,0.f,0.f,0.f,0.f,0.f,0.f,0.f,0.f,0.f,0.f,0.f,0.f};

  const int krow = t >> 2, kseg = (t & 3) * 8;   // stage K: 64 rows x 32
  const int krowp = (krow & 51) | ((krow & 4) << 1) | ((krow & 8) >> 1);  // tau
  const int vrow = t >> 3, vseg = (t & 7) * 8;   // stage V': 32 rows x 64
  const short* kgp = kb  + (size_t)head*NN*DKV;
  const short* vgp = vtb + (size_t)head*DKV*NN;

  *(short8*)(s_k + krowp*40 + kseg) = *(const short8*)(kgp + (size_t)krow*DKV + kseg);
  *(short8*)(s_vt + vrow*72 + vseg) = *(const short8*)(vgp + (size_t)vrow*NN + vseg);
  __syncthreads();

  for (int kc = 0; kc < 16; ++kc) {
    const int cur = kc & 1;
    short8 nk, nv;
    if (kc < 15) {
      nk = *(const short8*)(kgp + (size_t)((kc+1)*64 + krow)*DKV + kseg);
      nv = *(const short8*)(vgp + (size_t)vrow*NN + (kc+1)*64 + vseg);
    }

#pragma unroll
    for (int kt = 0; kt < 2; ++kt) {
      const short8 a0 = *(const short8*)(s_k + cur*2560 + (kt*32 + li)*40 + hi*8);
      const short8 a1 = *(const short8*)(s_k + cur*2560 + (kt*32 + li)*40 + 16 + hi*8);
      f32x16 sT = {0.f,0.f,0.f,0.f,0.f,0.f,0.f,0.f,0.f,0.f,0.f,0.f,0.f,0.f,0.f,0.f};
      sT = __builtin_amdgcn_mfma_f32_32x32x16_bf16(a0, qf0, sT, 0, 0, 0);
      sT = __builtin_amdgcn_mfma_f32_32x32x16_bf16(a1, qf1, sT, 0, 0, 0);
      // exp'd regs 0-7 / 8-15 ARE the PV A-frags (tau row permutation)
      short8 pa0, pa1;
#pragma unroll
      for (int j = 0; j < 8; ++j) {
        pa0[j] = bf16_of(__builtin_amdgcn_exp2f(sT[j]));
        pa1[j] = bf16_of(__builtin_amdgcn_exp2f(sT[8 + j]));
      }
      const short8 vfa = *(const short8*)(s_vt + cur*2304 + li*72 + kt*32 + hi*8);
      const short8 vfb = *(const short8*)(s_vt + cur*2304 + li*72 + kt*32 + 16 + hi*8);
      acc = __builtin_amdgcn_mfma_f32_32x32x16_bf16(pa0, vfa, acc, 0, 0, 0);
      acc = __builtin_amdgcn_mfma_f32_32x32x16_bf16(pa1, vfb, acc, 0, 0, 0);
    }

    if (kc < 15) {
      *(short8*)(s_k + (cur^1)*2560 + krowp*40 + kseg) = nk;
      *(short8*)(s_vt + (cur^1)*2304 + vrow*72 + vseg) = nv;
    }
    __syncthreads();
  }

  const int bc = head / NHH, h = head % NHH;
#pragma unroll
  for (int reg = 0; reg < 16; ++reg) {
    const int q = q0 + (reg & 3) + 8*(reg >> 2) + 4*hi;
    ctx[((size_t)(bc*NN + q))*ND + h*DKV + li] = bf16_of(acc[reg]);
  }

  // ---- ticket: release our slice, third finisher runs the epilogue
  __threadfence();                               // device-scope release
  if (t == 0) {
    int old = atomicAdd(&cnt[bc*8 + qtile], 1);
    s_flag = (old == 2);
  }
  __syncthreads();                               // also: all waves done with smem
  if (!s_flag) return;
  __threadfence();                               // acquire: see producers' ctx

  // ---- epilogue: out = LN(ctx @ Wfc^T + resid) for rows [qtile*128, +128)
  short* wlds = (short*)smem;                    // [96][104] = 19968B (reuse)
  for (int idx = t; idx < 96*96; idx += 256)
    wlds[(idx/96)*104 + idx%96] = bf16_of(Wfc[idx]);
  __syncthreads();

  const int g16 = lane >> 4, li16 = lane & 15;
#pragma unroll
  for (int half = 0; half < 2; ++half) {
    const int row0 = bc*NN + qtile*128 + half*64 + wave*16;

    const short* ar = ctx + (size_t)(row0 + li16)*ND + g16*8;
    const short8 a0 = *(const short8*)(ar);
    const short8 a1 = *(const short8*)(ar + 32);
    const short8 a2 = *(const short8*)(ar + 64);

    float o[6][4];
#pragma unroll
    for (int tt = 0; tt < 6; ++tt) {
      f32x4 oa = {0.f, 0.f, 0.f, 0.f};
      const short* wr = wlds + (tt*16 + li16)*104 + g16*8;
      oa = __builtin_amdgcn_mfma_f32_16x16x32_bf16(a0, *(const short8*)(wr),      oa, 0, 0, 0);
      oa = __builtin_amdgcn_mfma_f32_16x16x32_bf16(a1, *(const short8*)(wr + 32), oa, 0, 0, 0);
      oa = __builtin_amdgcn_mfma_f32_16x16x32_bf16(a2, *(const short8*)(wr + 64), oa, 0, 0, 0);
#pragma unroll
      for (int r = 0; r < 4; ++r)
        o[tt][r] = oa[r] + resid[(size_t)(row0 + g16*4 + r)*ND + tt*16 + li16];
    }

    float s1v[4], s2v[4];
#pragma unroll
    for (int r = 0; r < 4; ++r) {
      float a = 0.f, b = 0.f;
#pragma unroll
      for (int tt = 0; tt < 6; ++tt) { a += o[tt][r]; b += o[tt][r]*o[tt][r]; }
      s1v[r] = a; s2v[r] = b;
    }
#pragma unroll
    for (int ms = 1; ms <= 8; ms <<= 1) {
#pragma unroll
      for (int r = 0; r < 4; ++r) {
        s1v[r] += __shfl_xor(s1v[r], ms);
        s2v[r] += __shfl_xor(s2v[r], ms);
      }
    }
    float mean[4], rs[4];
#pragma unroll
    for (int r = 0; r < 4; ++r) {
      mean[r] = s1v[r] * (1.0f/96.0f);
      float var = s2v[r]*(1.0f/96.0f) - mean[r]*mean[r];
      rs[r] = rsqrtf(var + EPSV);
    }
#pragma unroll
    for (int tt = 0; tt < 6; ++tt) {
      const int e = tt*16 + li16;
      const float gg = gamma[e], bb = beta[e];
#pragma unroll
      for (int r = 0; r < 4; ++r)
        out[(size_t)(row0 + g16*4 + r)*ND + e] = (o[tt][r] - mean[r])*rs[r]*gg + bb;
    }
  }
}

// ---------------------------------------------------------------------------
extern "C" void kernel_launch(void* const* d_in, const int* in_sizes, int n_in,
                              void* d_out, int out_size, void* d_ws, size_t ws_size,
                              hipStream_t stream) {
  (void)in_sizes; (void)n_in; (void)out_size; (void)ws_size;
  const float* xq    = (const float*)d_in[0];
  const float* xk    = (const float*)d_in[1];
  const float* xv    = (const float*)d_in[2];
  const float* Wq    = (const float*)d_in[3];
  const float* Wk    = (const float*)d_in[4];
  const float* Wv    = (const float*)d_in[5];
  const float* Wfc   = (const float*)d_in[6];
  const float* gamma = (const float*)d_in[7];
  const float* beta  = (const float*)d_in[8];
  float* out = (float*)d_out;

  // Workspace (25.17 MB + 1KB tickets — ctx aliases vb, dead after stats;
  // proven safe since round 4).
  short* qb  = (short*)d_ws;                         // [head][n][32]
  short* kb  = qb  + (size_t)NHEAD*NN*DKV;           // [head][n][32] (x C1)
  short* vtb = kb  + (size_t)NHEAD*NN*DKV;           // [head][32][n] = is[k]*V
  short* vb  = vtb + (size_t)NHEAD*NN*DKV;           // [head][n][32] (dead after stats)
  short* ctx = vb;                                   // [bc*n][96] (aliases vb)
  int*   cnt = (int*)(vb + (size_t)NHEAD*NN*DKV);    // 256 tickets

  hipLaunchKernelGGL(proj_kernel,  dim3(3*NROWS/64), dim3(256), 0, stream,
                     xq, xk, xv, Wq, Wk, Wv, qb, kb, vb, cnt);
  hipLaunchKernelGGL(stats_kernel, dim3(NHEAD*16), dim3(256), 0, stream,
                     qb, kb, vb, vtb);
  hipLaunchKernelGGL(ctx_kernel,   dim3(NHEAD*8), dim3(256), 0, stream,
                     qb, kb, vtb, xq, Wfc, gamma, beta, ctx, cnt, out);
}

// Round 11
// 74.092 us; speedup vs baseline: 2.6747x; 2.6019x over previous
//
#include <hip/hip_runtime.h>
#include <hip/hip_bf16.h>

// Sizes
#define NB 8
#define NC 4
#define NN 1024
#define ND 96
#define NHH 3
#define DKV 32
#define NBC (NB*NC)        // 32
#define NHEAD (NBC*NHH)    // 96
#define NROWS (NBC*NN)     // 32768
// log2(e) / sqrt(32)  (folded into K at projection time)
#define C1 0.25503486910638953f
#define EPSV 1e-5f

using short8 = __attribute__((ext_vector_type(8))) short;
using f32x4  = __attribute__((ext_vector_type(4))) float;
using f32x16 = __attribute__((ext_vector_type(16))) float;

__device__ __forceinline__ short bf16_of(float f) {
  __hip_bfloat16 h = __float2bfloat16(f);
  return __builtin_bit_cast(short, h);
}
__device__ __forceinline__ float f_of_bf16(short s) {
  return __bfloat162float(__builtin_bit_cast(__hip_bfloat16, s));
}

__device__ __forceinline__ short8 load_cvt8(const float* p) {
  float4 f0 = *(const float4*)p;
  float4 f1 = *(const float4*)(p + 4);
  short8 v;
  v[0] = bf16_of(f0.x); v[1] = bf16_of(f0.y); v[2] = bf16_of(f0.z); v[3] = bf16_of(f0.w);
  v[4] = bf16_of(f1.x); v[5] = bf16_of(f1.y); v[6] = bf16_of(f1.z); v[7] = bf16_of(f1.w);
  return v;
}

// ---------------------------------------------------------------------------
// Kernel 1: projections, p split across blocks (each p reads a DIFFERENT x).
// W + x staged in LDS. grid 1536 = 3 x 512, block 256.
// ---------------------------------------------------------------------------
__global__ __launch_bounds__(256) void proj_kernel(
    const float* __restrict__ xq, const float* __restrict__ xk, const float* __restrict__ xv,
    const float* __restrict__ Wq, const float* __restrict__ Wk, const float* __restrict__ Wv,
    short* __restrict__ qb, short* __restrict__ kb, short* __restrict__ vb)
{
  __shared__ __align__(16) short wlds[96][104];
  __shared__ __align__(16) short xlds[64][104];
  const int t = threadIdx.x;
  const int p = blockIdx.x >> 9;               // 0..2
  const int blkrow0 = (blockIdx.x & 511) * 64;

  const float* x = (p == 0) ? xq : (p == 1) ? xk : xv;
  const float* W = (p == 0) ? Wq : (p == 1) ? Wk : Wv;
  short* dst = (p == 0) ? qb : (p == 1) ? kb : vb;
  const float sc = (p == 1) ? C1 : 1.0f;

  for (int idx = t; idx < 96*96; idx += 256)
    wlds[idx/96][idx%96] = bf16_of(W[idx]);
#pragma unroll
  for (int it = 0; it < 3; ++it) {
    const int f = it*2048 + t*8;               // 96%8==0: no row straddle
    const int row = f / 96, col = f % 96;
    *(short8*)&xlds[row][col] = load_cvt8(x + (size_t)(blkrow0 + row)*ND + col);
  }
  __syncthreads();

  const int wave = t >> 6, lane = t & 63;
  const int g = lane >> 4, li = lane & 15;
  const int row0 = blkrow0 + wave * 16;
  const int acol = g * 8;

  const short8 a0 = *(const short8*)&xlds[wave*16 + li][acol];
  const short8 a1 = *(const short8*)&xlds[wave*16 + li][32 + acol];
  const short8 a2 = *(const short8*)&xlds[wave*16 + li][64 + acol];
#pragma unroll
  for (int tt = 0; tt < 6; ++tt) {
    f32x4 acc = {0.f, 0.f, 0.f, 0.f};
    const short* wr = &wlds[tt*16 + li][acol];
    acc = __builtin_amdgcn_mfma_f32_16x16x32_bf16(a0, *(const short8*)(wr),      acc, 0, 0, 0);
    acc = __builtin_amdgcn_mfma_f32_16x16x32_bf16(a1, *(const short8*)(wr + 32), acc, 0, 0, 0);
    acc = __builtin_amdgcn_mfma_f32_16x16x32_bf16(a2, *(const short8*)(wr + 64), acc, 0, 0, 0);
    const int e = tt*16 + li;
    const int h = e >> 5, dd = e & 31;
#pragma unroll
    for (int r = 0; r < 4; ++r) {
      const int n = row0 + g*4 + r;
      const int bc = n >> 10, nn = n & 1023;
      const int head = bc*NHH + h;
      dst[((size_t)head*NN + nn)*DKV + dd] = bf16_of(acc[r] * sc);
    }
  }
}

// ---------------------------------------------------------------------------
// Kernel 2: column softmax sums + V' = diag(1/sum)*V transposed.
// 64 k per block (wave owns 16 k-rows), Q chunks double-buffered in LDS.
// T5: setprio(1) around the MFMA+exp cluster.
// XCD-aware: head = blockIdx%96. grid 96*16, block 256.
// ---------------------------------------------------------------------------
__global__ __launch_bounds__(256) void stats_kernel(
    const short* __restrict__ qb, const short* __restrict__ kb,
    const short* __restrict__ vb, short* __restrict__ vtb)
{
  __shared__ __align__(16) short s_q[2][64][40];
  __shared__ float s_is[64];
  __shared__ __align__(16) short s_t[32][64];    // V' transpose buf (swizzled)

  const int t = threadIdx.x, wave = t >> 6, lane = t & 63;
  const int g = lane >> 4, li = lane & 15;
  const int head = blockIdx.x % NHEAD;           // XCD-aware
  const int kblk = blockIdx.x / NHEAD;           // 0..15
  const int kb0 = kblk*64;
  const int k0 = kb0 + wave*16;

  const short8 af = *(const short8*)(kb + ((size_t)head*NN + k0 + li)*DKV + g*8);

  const short* qhead = qb + (size_t)head*NN*DKV;
  const int srow = t >> 2;          // 0..63
  const int sseg = (t & 3) * 8;

  f32x4 s0 = {0.f,0.f,0.f,0.f};

  *(short8*)&s_q[0][srow][sseg] = *(const short8*)(qhead + (size_t)srow*DKV + sseg);
  __syncthreads();

  for (int qc = 0; qc < 16; ++qc) {
    const int cur = qc & 1;
    short8 nxt;
    if (qc < 15)
      nxt = *(const short8*)(qhead + (size_t)((qc+1)*64 + srow)*DKV + sseg);
    __builtin_amdgcn_s_setprio(1);
#pragma unroll
    for (int qt = 0; qt < 4; ++qt) {
      const short8 bf = *(const short8*)&s_q[cur][qt*16 + li][g*8];
      f32x4 z = {0.f,0.f,0.f,0.f};
      f32x4 d = __builtin_amdgcn_mfma_f32_16x16x32_bf16(af, bf, z, 0, 0, 0);
#pragma unroll
      for (int r = 0; r < 4; ++r)
        s0[r] += __builtin_amdgcn_exp2f(d[r]);
    }
    __builtin_amdgcn_s_setprio(0);
    if (qc < 15)
      *(short8*)&s_q[cur^1][srow][sseg] = nxt;
    __syncthreads();
  }

#pragma unroll
  for (int ms = 1; ms <= 8; ms <<= 1) {
#pragma unroll
    for (int r = 0; r < 4; ++r)
      s0[r] += __shfl_xor(s0[r], ms);
  }
  if (li == 0) {
#pragma unroll
    for (int r = 0; r < 4; ++r)
      s_is[wave*16 + g*4 + r] = 1.0f / s0[r];
  }
  __syncthreads();

  // ---- V' phase A: read vb rows, scale by is[n], scatter into LDS transpose
  {
    const int nl = t >> 2;              // 0..63 (local k)
    const int dvs = (t & 3) * 8;        // dv segment base
    const float isv = s_is[nl];
    const short* vrow = vb + ((size_t)head*NN + kb0 + nl)*DKV + dvs;
    short8 v0 = *(const short8*)(vrow);
    short* st = &s_t[0][0];
#pragma unroll
    for (int j = 0; j < 8; ++j) {
      const int dv = dvs + j;
      st[dv*64 + (((nl*2) ^ ((dv & 7) << 4)) >> 1)] = bf16_of(isv * f_of_bf16(v0[j]));
    }
  }
  __syncthreads();

  // ---- V' phase B: coalesced write to vtb [head][dv][n]
  {
    const short* st = &s_t[0][0];
    const int dv = t >> 3, ns = t & 7;
    short8 v = *(const short8*)(st + dv*64 + (((ns*16) ^ ((dv & 7) << 4)) >> 1));
    *(short8*)(vtb + ((size_t)head*DKV + dv)*NN + kb0 + ns*8) = v;
  }
}

// ---------------------------------------------------------------------------
// Kernel 3: context. 32x32x16 MFMAs; K-tile rows staged with tau (swap bits
// 2<->3) so exp'd S^T regs ARE the PV A-fragments (P never touches LDS).
// 128-thread blocks (2 waves, 64 q): 6 blocks/CU. T5: setprio around the
// MFMA+exp cluster (blocks at independent phases -> arbitration pays).
// XCD-aware: head = blockIdx%96. grid 96*16, block 128.
// ---------------------------------------------------------------------------
__global__ __launch_bounds__(128) void ctx_kernel(
    const short* __restrict__ qb, const short* __restrict__ kb,
    const short* __restrict__ vtb, short* __restrict__ ctx)
{
  __shared__ __align__(16) short s_k[2][64][40];   // 80B rows: conflict-free
  __shared__ __align__(16) short s_vt[2][32][72];  // 144B rows: conflict-free

  const int t = threadIdx.x, wave = t >> 6, lane = t & 63;
  const int li = lane & 31, hi = lane >> 5;
  const int head = blockIdx.x % NHEAD;             // XCD-aware
  const int qtile = blockIdx.x / NHEAD;            // 0..15
  const int q0 = qtile*64 + wave*32;

  const short* qrow = qb + ((size_t)head*NN + q0 + li)*DKV;
  const short8 qf0 = *(const short8*)(qrow + hi*8);
  const short8 qf1 = *(const short8*)(qrow + 16 + hi*8);

  f32x16 acc = {0.f,0.f,0.f,0.f,0.f,0.f,0.f,0.f,0.f,0.f,0.f,0.f,0.f,0.f,0.f,0.f};

  const int krow = t >> 1, ksegb = (t & 1) * 16;  // stage K: 64 rows x 32, 16/thread
  // tau: destination row — swap bits 2,3 (involution)
  const int krowp = (krow & 51) | ((krow & 4) << 1) | ((krow & 8) >> 1);
  const int vrow = t >> 2, vsegb = (t & 3) * 16;  // stage V': 32 rows x 64, 16/thread
  const short* kgp = kb  + (size_t)head*NN*DKV;
  const short* vgp = vtb + (size_t)head*DKV*NN;

  *(short8*)&s_k[0][krowp][ksegb]      = *(const short8*)(kgp + (size_t)krow*DKV + ksegb);
  *(short8*)&s_k[0][krowp][ksegb + 8]  = *(const short8*)(kgp + (size_t)krow*DKV + ksegb + 8);
  *(short8*)&s_vt[0][vrow][vsegb]      = *(const short8*)(vgp + (size_t)vrow*NN + vsegb);
  *(short8*)&s_vt[0][vrow][vsegb + 8]  = *(const short8*)(vgp + (size_t)vrow*NN + vsegb + 8);
  __syncthreads();

  for (int kc = 0; kc < 16; ++kc) {
    const int cur = kc & 1;
    short8 nk0, nk1, nv0, nv1;
    if (kc < 15) {
      nk0 = *(const short8*)(kgp + (size_t)((kc+1)*64 + krow)*DKV + ksegb);
      nk1 = *(const short8*)(kgp + (size_t)((kc+1)*64 + krow)*DKV + ksegb + 8);
      nv0 = *(const short8*)(vgp + (size_t)vrow*NN + (kc+1)*64 + vsegb);
      nv1 = *(const short8*)(vgp + (size_t)vrow*NN + (kc+1)*64 + vsegb + 8);
    }

    __builtin_amdgcn_s_setprio(1);
#pragma unroll
    for (int kt = 0; kt < 2; ++kt) {
      const short8 a0 = *(const short8*)&s_k[cur][kt*32 + li][hi*8];
      const short8 a1 = *(const short8*)&s_k[cur][kt*32 + li][16 + hi*8];
      f32x16 sT = {0.f,0.f,0.f,0.f,0.f,0.f,0.f,0.f,0.f,0.f,0.f,0.f,0.f,0.f,0.f,0.f};
      sT = __builtin_amdgcn_mfma_f32_32x32x16_bf16(a0, qf0, sT, 0, 0, 0);
      sT = __builtin_amdgcn_mfma_f32_32x32x16_bf16(a1, qf1, sT, 0, 0, 0);
      // exp2 -> bf16: regs 0-7 are PV A-frag for k-block kt*32+[0,16),
      // regs 8-15 for kt*32+[16,32) (tau row permutation).
      short8 pa0, pa1;
#pragma unroll
      for (int j = 0; j < 8; ++j) {
        pa0[j] = bf16_of(__builtin_amdgcn_exp2f(sT[j]));
        pa1[j] = bf16_of(__builtin_amdgcn_exp2f(sT[8 + j]));
      }
      const short8 vfa = *(const short8*)&s_vt[cur][li][kt*32 + hi*8];
      const short8 vfb = *(const short8*)&s_vt[cur][li][kt*32 + 16 + hi*8];
      acc = __builtin_amdgcn_mfma_f32_32x32x16_bf16(pa0, vfa, acc, 0, 0, 0);
      acc = __builtin_amdgcn_mfma_f32_32x32x16_bf16(pa1, vfb, acc, 0, 0, 0);
    }
    __builtin_amdgcn_s_setprio(0);

    if (kc < 15) {
      *(short8*)&s_k[cur^1][krowp][ksegb]     = nk0;
      *(short8*)&s_k[cur^1][krowp][ksegb + 8] = nk1;
      *(short8*)&s_vt[cur^1][vrow][vsegb]     = nv0;
      *(short8*)&s_vt[cur^1][vrow][vsegb + 8] = nv1;
    }
    __syncthreads();
  }

  const int bc = head / NHH, h = head % NHH;
#pragma unroll
  for (int reg = 0; reg < 16; ++reg) {
    const int q = q0 + (reg & 3) + 8*(reg >> 2) + 4*hi;
    ctx[((size_t)(bc*NN + q))*ND + h*DKV + li] = bf16_of(acc[reg]);
  }
}

// ---------------------------------------------------------------------------
// Kernel 4: out = LN(ctx @ Wfc^T + input_Q).
// ---------------------------------------------------------------------------
__global__ __launch_bounds__(256) void out_kernel(
    const short* __restrict__ ctx, const float* __restrict__ Wfc,
    const float* __restrict__ resid, const float* __restrict__ gamma,
    const float* __restrict__ beta, float* __restrict__ out)
{
  __shared__ __align__(16) short wlds[96][104];
  const int t = threadIdx.x;
  for (int idx = t; idx < 96*96; idx += 256)
    wlds[idx/96][idx%96] = bf16_of(Wfc[idx]);
  __syncthreads();

  const int wave = t >> 6, lane = t & 63;
  const int g = lane >> 4, li = lane & 15;
  const int row0 = blockIdx.x * 64 + wave * 16;

  const short* ar = ctx + (size_t)(row0 + li)*ND + g*8;
  const short8 a0 = *(const short8*)(ar);
  const short8 a1 = *(const short8*)(ar + 32);
  const short8 a2 = *(const short8*)(ar + 64);

  float o[6][4];
#pragma unroll
  for (int tt = 0; tt < 6; ++tt) {
    f32x4 acc = {0.f, 0.f, 0.f, 0.f};
    const short* wr = &wlds[tt*16 + li][g*8];
    acc = __builtin_amdgcn_mfma_f32_16x16x32_bf16(a0, *(const short8*)(wr),      acc, 0, 0, 0);
    acc = __builtin_amdgcn_mfma_f32_16x16x32_bf16(a1, *(const short8*)(wr + 32), acc, 0, 0, 0);
    acc = __builtin_amdgcn_mfma_f32_16x16x32_bf16(a2, *(const short8*)(wr + 64), acc, 0, 0, 0);
#pragma unroll
    for (int r = 0; r < 4; ++r)
      o[tt][r] = acc[r] + resid[(size_t)(row0 + g*4 + r)*ND + tt*16 + li];
  }

  float s1v[4], s2v[4];
#pragma unroll
  for (int r = 0; r < 4; ++r) {
    float a = 0.f, b = 0.f;
#pragma unroll
    for (int tt = 0; tt < 6; ++tt) { a += o[tt][r]; b += o[tt][r]*o[tt][r]; }
    s1v[r] = a; s2v[r] = b;
  }
#pragma unroll
  for (int ms = 1; ms <= 8; ms <<= 1) {
#pragma unroll
    for (int r = 0; r < 4; ++r) {
      s1v[r] += __shfl_xor(s1v[r], ms);
      s2v[r] += __shfl_xor(s2v[r], ms);
    }
  }
  float mean[4], rs[4];
#pragma unroll
  for (int r = 0; r < 4; ++r) {
    mean[r] = s1v[r] * (1.0f/96.0f);
    float var = s2v[r]*(1.0f/96.0f) - mean[r]*mean[r];
    rs[r] = rsqrtf(var + EPSV);
  }
#pragma unroll
  for (int tt = 0; tt < 6; ++tt) {
    const int e = tt*16 + li;
    const float gg = gamma[e], bb = beta[e];
#pragma unroll
    for (int r = 0; r < 4; ++r)
      out[(size_t)(row0 + g*4 + r)*ND + e] = (o[tt][r] - mean[r])*rs[r]*gg + bb;
  }
}

// ---------------------------------------------------------------------------
extern "C" void kernel_launch(void* const* d_in, const int* in_sizes, int n_in,
                              void* d_out, int out_size, void* d_ws, size_t ws_size,
                              hipStream_t stream) {
  (void)in_sizes; (void)n_in; (void)out_size; (void)ws_size;
  const float* xq    = (const float*)d_in[0];
  const float* xk    = (const float*)d_in[1];
  const float* xv    = (const float*)d_in[2];
  const float* Wq    = (const float*)d_in[3];
  const float* Wk    = (const float*)d_in[4];
  const float* Wv    = (const float*)d_in[5];
  const float* Wfc   = (const float*)d_in[6];
  const float* gamma = (const float*)d_in[7];
  const float* beta  = (const float*)d_in[8];
  float* out = (float*)d_out;

  // Workspace layout (25.17 MB total — ctx aliases vb, dead after stats;
  // proven safe since round 4).
  short* qb  = (short*)d_ws;                         // [head][n][32]
  short* kb  = qb  + (size_t)NHEAD*NN*DKV;           // [head][n][32] (x C1)
  short* vtb = kb  + (size_t)NHEAD*NN*DKV;           // [head][32][n] = is[k]*V
  short* vb  = vtb + (size_t)NHEAD*NN*DKV;           // [head][n][32] (dead after stats)
  short* ctx = vb;                                   // [bc*n][96] (aliases vb)

  hipLaunchKernelGGL(proj_kernel,  dim3(3*NROWS/64), dim3(256), 0, stream,
                     xq, xk, xv, Wq, Wk, Wv, qb, kb, vb);
  hipLaunchKernelGGL(stats_kernel, dim3(NHEAD*16), dim3(256), 0, stream,
                     qb, kb, vb, vtb);
  hipLaunchKernelGGL(ctx_kernel,   dim3(NHEAD*16), dim3(128), 0, stream,
                     qb, kb, vtb, ctx);
  hipLaunchKernelGGL(out_kernel,   dim3(NROWS/64), dim3(256), 0, stream,
                     ctx, Wfc, xq, gamma, beta, out);
}